// Round 1
// baseline (3071.981 us; speedup 1.0000x reference)
//
#include <hip/hip_runtime.h>
#include <stdint.h>

#define BB 16
#define EE 256
#define TT 4096
#define FF 512
#define RK 10
#define NIT 5

__device__ __forceinline__ unsigned short f2bf(float x){
  unsigned int u = __float_as_uint(x);
  unsigned int r = (u + 0x7FFFu + ((u >> 16) & 1u)) >> 16;
  return (unsigned short)r;
}
__device__ __forceinline__ float bf2f(unsigned short s){
  return __uint_as_float(((unsigned int)s) << 16);
}

// ---------------- setup kernels ----------------

__global__ void k_params(const float* lam_log, const float* mu_log,
                         const float* nu_log, const float* gl, float* prm){
  int k = threadIdx.x;
  if (k < NIT){
    float lam = expf(lam_log[k]);
    float mu  = expf(mu_log[k]);
    float nu  = expf(nu_log[k]);
    float gam = 1.0f/(1.0f+expf(-gl[k]));
    prm[k*8+0]=lam; prm[k*8+1]=mu; prm[k*8+2]=nu; prm[k*8+3]=gam; prm[k*8+4]=lam/nu;
  }
}

__global__ void k_initX(const float4* __restrict__ Y, const float4* __restrict__ Om,
                        float4* __restrict__ X){
  int i = blockIdx.x*256 + threadIdx.x;
  float4 y = Y[i], o = Om[i];
  X[i] = make_float4(y.x*o.x, y.y*o.y, y.z*o.z, y.w*o.w);
}

__global__ void k_qtrans(const float* __restrict__ Q0, float* __restrict__ Qt){
  int idx = blockIdx.x*256 + threadIdx.x;   // b*TT + t
  int b = idx >> 12, t = idx & (TT-1);
  #pragma unroll
  for (int j=0;j<RK;j++)
    Qt[((size_t)b*RK + j)*TT + t] = Q0[(size_t)idx*RK + j];
}

__global__ void k_rtrans(const float* __restrict__ Rm, float* __restrict__ Rt){
  int f = blockIdx.x, b = blockIdx.y, e = threadIdx.x;
  Rt[((size_t)b*FF + f)*EE + e] = Rm[((size_t)b*EE + e)*FF + f];
}

// A_scale = (R*R)^T @ (Om*Om), stored bf16 (counts <=256 exact)
__global__ void k_ascale(const float* __restrict__ Rt, const float* __restrict__ Om,
                         unsigned short* __restrict__ As){
  int f = blockIdx.x, b = blockIdx.z;
  int t = blockIdx.y*1024 + threadIdx.x*4;
  __shared__ int s_cnt;
  __shared__ short s_idx[EE];
  __shared__ float s_w[EE];
  if (threadIdx.x==0) s_cnt = 0;
  __syncthreads();
  {
    int e = threadIdx.x;
    float w = Rt[((size_t)b*FF + f)*EE + e];
    if (w != 0.0f){ int p = atomicAdd(&s_cnt,1); s_idx[p]=(short)e; s_w[p]=w*w; }
  }
  __syncthreads();
  int cnt = s_cnt;
  float4 acc = {0,0,0,0};
  const float* Ob = Om + (size_t)b*EE*TT + t;
  for (int it=0; it<cnt; ++it){
    int e = s_idx[it]; float w2 = s_w[it];
    float4 o = *(const float4*)(Ob + (size_t)e*TT);
    acc.x += w2*o.x*o.x; acc.y += w2*o.y*o.y; acc.z += w2*o.z*o.z; acc.w += w2*o.w*o.w;
  }
  ushort4 r; r.x=f2bf(acc.x); r.y=f2bf(acc.y); r.z=f2bf(acc.z); r.w=f2bf(acc.w);
  *(ushort4*)(As + ((size_t)b*FF + f)*TT + t) = r;
}

// ---------------- per-iteration small kernels ----------------

// lhs[i][j] = sum_t Qt[i,t]*Qt[j,t] (+regp on diag); grid (55, B)
__global__ void k_lhsQ(const float* __restrict__ Qt, const float* __restrict__ prm,
                       float* __restrict__ lhs, int k){
  int p = blockIdx.x, b = blockIdx.y;
  int i = 0, rem = p;
  while (rem >= i+1){ rem -= (i+1); ++i; }
  int j = rem;
  const float* qi = Qt + ((size_t)b*RK + i)*TT;
  const float* qj = Qt + ((size_t)b*RK + j)*TT;
  float a = 0.0f;
  for (int t = threadIdx.x*4; t < TT; t += 1024){
    float4 x = *(const float4*)(qi+t);
    float4 y = *(const float4*)(qj+t);
    a += x.x*y.x + x.y*y.y + x.z*y.z + x.w*y.w;
  }
  __shared__ float red[256];
  red[threadIdx.x] = a; __syncthreads();
  for (int s=128; s>0; s>>=1){
    if (threadIdx.x < s) red[threadIdx.x] += red[threadIdx.x+s];
    __syncthreads();
  }
  if (threadIdx.x==0){
    float v = red[0];
    if (i==j) v += prm[k*8+4];
    lhs[(b*RK+i)*RK + j] = v;
    lhs[(b*RK+j)*RK + i] = v;
  }
}

// lhs[i][j] = sum_e P[e,i]*P[e,j] (+regp); grid (55, B)
__global__ void k_lhsP(const float* __restrict__ P, const float* __restrict__ prm,
                       float* __restrict__ lhs, int k){
  int p = blockIdx.x, b = blockIdx.y;
  int i = 0, rem = p;
  while (rem >= i+1){ rem -= (i+1); ++i; }
  int j = rem;
  int e = threadIdx.x;
  const float* pr = P + ((size_t)b*EE + e)*RK;
  float a = pr[i]*pr[j];
  __shared__ float red[256];
  red[threadIdx.x] = a; __syncthreads();
  for (int s=128; s>0; s>>=1){
    if (threadIdx.x < s) red[threadIdx.x] += red[threadIdx.x+s];
    __syncthreads();
  }
  if (threadIdx.x==0){
    float v = red[0];
    if (i==j) v += prm[k*8+4];
    lhs[(b*RK+i)*RK + j] = v;
    lhs[(b*RK+j)*RK + i] = v;
  }
}

// 10x10 Gauss-Jordan inverse (SPD, no pivoting); grid B, block 256 (200 active)
__global__ void k_invert(const float* __restrict__ lhs, float* __restrict__ inv){
  int b = blockIdx.x;
  __shared__ float aug[RK][2*RK];
  int tid = threadIdx.x;
  int i = tid / (2*RK), j = tid % (2*RK);
  bool act = tid < RK*2*RK;
  if (act) aug[i][j] = (j < RK) ? lhs[(b*RK+i)*RK + j] : ((j-RK)==i ? 1.0f : 0.0f);
  __syncthreads();
  for (int kk=0; kk<RK; ++kk){
    float pinv = 1.0f / aug[kk][kk];
    __syncthreads();
    if (act && i==kk) aug[i][j] *= pinv;
    __syncthreads();
    float factor = (act && i!=kk) ? aug[i][kk] : 0.0f;
    float pivrow = act ? aug[kk][j] : 0.0f;
    __syncthreads();
    if (act && i!=kk) aug[i][j] -= factor * pivrow;
    __syncthreads();
  }
  if (act && j >= RK) inv[(b*RK+i)*RK + (j-RK)] = aug[i][j];
}

// P[e,:] = (sum_t X[e,t]*Qt[:,t]) @ invQ ; grid (E, B)
__global__ void k_Pupd(const float* __restrict__ X, const float* __restrict__ Qt,
                       const float* __restrict__ inv, float* __restrict__ P){
  int e = blockIdx.x, b = blockIdx.y;
  const float* xr = X + ((size_t)b*EE + e)*TT;
  const float* qb = Qt + (size_t)b*RK*TT;
  float acc[RK];
  #pragma unroll
  for (int j=0;j<RK;j++) acc[j]=0.0f;
  for (int t = threadIdx.x*4; t < TT; t += 1024){
    float4 x = *(const float4*)(xr+t);
    #pragma unroll
    for (int j=0;j<RK;j++){
      float4 q = *(const float4*)(qb + (size_t)j*TT + t);
      acc[j] += x.x*q.x + x.y*q.y + x.z*q.z + x.w*q.w;
    }
  }
  __shared__ float partial[4][RK];
  int lane = threadIdx.x & 63, wv = threadIdx.x >> 6;
  #pragma unroll
  for (int j=0;j<RK;j++){
    float v = acc[j];
    for (int s=32;s>0;s>>=1) v += __shfl_down(v, s, 64);
    if (lane==0) partial[wv][j] = v;
  }
  __syncthreads();
  if (threadIdx.x < RK){
    int i = threadIdx.x;
    float out = 0.0f;
    #pragma unroll
    for (int j=0;j<RK;j++){
      float xq = partial[0][j]+partial[1][j]+partial[2][j]+partial[3][j];
      out += xq * inv[(b*RK+j)*RK + i];
    }
    P[((size_t)b*EE + e)*RK + i] = out;
  }
}

// Qt[i,t] = (sum_e X[e,t]*P[e,:]) @ invP ; grid (T/256, B)
__global__ void k_Qupd(const float* __restrict__ X, const float* __restrict__ P,
                       const float* __restrict__ inv, float* __restrict__ Qt){
  int b = blockIdx.y;
  int t = blockIdx.x*256 + threadIdx.x;
  __shared__ float sP[EE*RK];
  __shared__ float sInv[RK*RK];
  for (int i=threadIdx.x; i<EE*RK; i+=256) sP[i] = P[(size_t)b*EE*RK + i];
  if (threadIdx.x < RK*RK) sInv[threadIdx.x] = inv[b*RK*RK + threadIdx.x];
  __syncthreads();
  float acc[RK];
  #pragma unroll
  for (int j=0;j<RK;j++) acc[j]=0.0f;
  const float* xb = X + (size_t)b*EE*TT + t;
  for (int e=0;e<EE;e++){
    float x = xb[(size_t)e*TT];
    #pragma unroll
    for (int j=0;j<RK;j++) acc[j] += x * sP[e*RK+j];
  }
  #pragma unroll
  for (int i=0;i<RK;i++){
    float q = 0.0f;
    #pragma unroll
    for (int j=0;j<RK;j++) q += acc[j]*sInv[j*RK+i];
    Qt[((size_t)b*RK + i)*TT + t] = q;
  }
}

// ---------------- big fused kernels ----------------

// RA = R@A (sparse row-sum), fused X-update + resid; grid (E, T/1024, B)
__global__ void k_gemm1(const float* __restrict__ Rm, const float* __restrict__ A,
                        const float* __restrict__ Y, const float* __restrict__ Om,
                        const float* __restrict__ Qt, const float* __restrict__ P,
                        const float* __restrict__ prm, float* __restrict__ X,
                        float* __restrict__ resid, int k){
  int e = blockIdx.x, b = blockIdx.z;
  int t = blockIdx.y*1024 + threadIdx.x*4;
  __shared__ int s_cnt;
  __shared__ short s_idx[FF];
  __shared__ float s_w[FF];
  __shared__ float sPe[RK];
  if (threadIdx.x==0) s_cnt = 0;
  __syncthreads();
  {
    const float* rrow = Rm + ((size_t)b*EE + e)*FF;
    for (int f=threadIdx.x; f<FF; f+=256){
      float w = rrow[f];
      if (w != 0.0f){ int p = atomicAdd(&s_cnt,1); s_idx[p]=(short)f; s_w[p]=w; }
    }
    if (threadIdx.x < RK) sPe[threadIdx.x] = P[((size_t)b*EE + e)*RK + threadIdx.x];
  }
  __syncthreads();
  int cnt = s_cnt;
  float4 ra = {0,0,0,0};
  const float* Ab = A + (size_t)b*FF*TT + t;
  for (int it=0; it<cnt; ++it){
    int f = s_idx[it]; float w = s_w[it];
    float4 a4 = *(const float4*)(Ab + (size_t)f*TT);
    ra.x += w*a4.x; ra.y += w*a4.y; ra.z += w*a4.z; ra.w += w*a4.w;
  }
  float4 pq = {0,0,0,0};
  const float* qb = Qt + (size_t)b*RK*TT + t;
  #pragma unroll
  for (int j=0;j<RK;j++){
    float4 q = *(const float4*)(qb + (size_t)j*TT);
    float pj = sPe[j];
    pq.x += pj*q.x; pq.y += pj*q.y; pq.z += pj*q.z; pq.w += pj*q.w;
  }
  float nu = prm[k*8+2];
  size_t off = ((size_t)b*EE + e)*TT + t;
  float4 y = *(const float4*)(Y + off);
  float4 o = *(const float4*)(Om + off);
  float4 xo, ro;
  {
    float d  = y.x - ra.x, om2 = o.x*o.x;
    xo.x = (om2*d + nu*pq.x) / (om2 + nu);
    ro.x = o.x*(y.x - xo.x - ra.x);
  }{
    float d  = y.y - ra.y, om2 = o.y*o.y;
    xo.y = (om2*d + nu*pq.y) / (om2 + nu);
    ro.y = o.y*(y.y - xo.y - ra.y);
  }{
    float d  = y.z - ra.z, om2 = o.z*o.z;
    xo.z = (om2*d + nu*pq.z) / (om2 + nu);
    ro.z = o.z*(y.z - xo.z - ra.z);
  }{
    float d  = y.w - ra.w, om2 = o.w*o.w;
    xo.w = (om2*d + nu*pq.w) / (om2 + nu);
    ro.w = o.w*(y.w - xo.w - ra.w);
  }
  *(float4*)(X + off) = xo;
  *(float4*)(resid + off) = ro;
}

__device__ __forceinline__ float aupd(float a, float g, unsigned short asu,
                                      float mu, float gamma){
  float as = bf2f(asu);
  bool no = (as == 0.0f);
  float rs = 1.0f / (no ? 1.0f : as);
  float ba = a + g*rs;
  float ad = copysignf(fmaxf(fabsf(ba) - mu*rs, 0.0f), ba);
  if (no) ad = 0.0f;
  return a + gamma*(ad - a);
}

// G = R^T@resid (sparse row-sum), fused A soft-threshold update; grid (F, T/1024, B)
__global__ void k_gemm2(const float* __restrict__ Rt, const float* __restrict__ resid,
                        const unsigned short* __restrict__ As,
                        const float* __restrict__ prm, float* __restrict__ A, int k){
  int f = blockIdx.x, b = blockIdx.z;
  int t = blockIdx.y*1024 + threadIdx.x*4;
  __shared__ int s_cnt;
  __shared__ short s_idx[EE];
  __shared__ float s_w[EE];
  if (threadIdx.x==0) s_cnt = 0;
  __syncthreads();
  {
    int e = threadIdx.x;
    float w = Rt[((size_t)b*FF + f)*EE + e];
    if (w != 0.0f){ int p = atomicAdd(&s_cnt,1); s_idx[p]=(short)e; s_w[p]=w; }
  }
  __syncthreads();
  int cnt = s_cnt;
  float4 g = {0,0,0,0};
  const float* rb = resid + (size_t)b*EE*TT + t;
  for (int it=0; it<cnt; ++it){
    int e = s_idx[it]; float w = s_w[it];
    float4 r4 = *(const float4*)(rb + (size_t)e*TT);
    g.x += w*r4.x; g.y += w*r4.y; g.z += w*r4.z; g.w += w*r4.w;
  }
  float mu = prm[k*8+1], gamma = prm[k*8+3];
  size_t off = ((size_t)b*FF + f)*TT + t;
  ushort4 asv = *(const ushort4*)(As + off);
  float4 a = *(float4*)(A + off);
  float4 an;
  an.x = aupd(a.x, g.x, asv.x, mu, gamma);
  an.y = aupd(a.y, g.y, asv.y, mu, gamma);
  an.z = aupd(a.z, g.z, asv.z, mu, gamma);
  an.w = aupd(a.w, g.w, asv.w, mu, gamma);
  *(float4*)(A + off) = an;
}

// ---------------- launch ----------------

extern "C" void kernel_launch(void* const* d_in, const int* in_sizes, int n_in,
                              void* d_out, int out_size, void* d_ws, size_t ws_size,
                              hipStream_t stream){
  const float* Y   = (const float*)d_in[0];
  const float* Rm  = (const float*)d_in[1];
  const float* Om  = (const float*)d_in[2];
  const float* P0  = (const float*)d_in[3];   // unused beyond P init path below
  const float* Q0  = (const float*)d_in[4];
  const float* lam = (const float*)d_in[5];
  const float* mu  = (const float*)d_in[6];
  const float* nu  = (const float*)d_in[7];
  const float* gl  = (const float*)d_in[8];
  float* A = (float*)d_out;

  char* ws = (char*)d_ws;
  const size_t X_OFF   = 0;
  const size_t RES_OFF = X_OFF   + (size_t)BB*EE*TT*4;   //  67108864
  const size_t AS_OFF  = RES_OFF + (size_t)BB*EE*TT*4;   // 134217728
  const size_t RT_OFF  = AS_OFF  + (size_t)BB*FF*TT*2;   // 201326592
  const size_t QT_OFF  = RT_OFF  + (size_t)BB*FF*EE*4;   // 209715200
  const size_t P_OFF   = QT_OFF  + (size_t)BB*RK*TT*4;   // 212336640
  const size_t LHS_OFF = P_OFF   + (size_t)BB*EE*RK*4;   // 212500480
  const size_t INV_OFF = LHS_OFF + (size_t)BB*RK*RK*4;   // 212506880
  const size_t PRM_OFF = INV_OFF + (size_t)BB*RK*RK*4;   // 212513280

  float* X    = (float*)(ws + X_OFF);
  float* resid= (float*)(ws + RES_OFF);
  unsigned short* As = (unsigned short*)(ws + AS_OFF);
  float* Rt   = (float*)(ws + RT_OFF);
  float* Qt   = (float*)(ws + QT_OFF);
  float* P    = (float*)(ws + P_OFF);
  float* lhs  = (float*)(ws + LHS_OFF);
  float* inv  = (float*)(ws + INV_OFF);
  float* prm  = (float*)(ws + PRM_OFF);

  (void)P0; (void)in_sizes; (void)n_in; (void)ws_size;

  hipMemsetAsync(d_out, 0, (size_t)out_size*sizeof(float), stream);
  k_params<<<1, 64, 0, stream>>>(lam, mu, nu, gl, prm);
  k_initX<<<BB*EE*TT/4/256, 256, 0, stream>>>((const float4*)Y, (const float4*)Om, (float4*)X);
  k_qtrans<<<BB*TT/256, 256, 0, stream>>>(Q0, Qt);
  k_rtrans<<<dim3(FF, BB), 256, 0, stream>>>(Rm, Rt);
  k_ascale<<<dim3(FF, TT/1024, BB), 256, 0, stream>>>(Rt, Om, As);

  // Note: reference initializes P=P0 but P is overwritten by the first P-update
  // before any use, so P0 only matters through... it does not: P-update uses X and Q only.
  for (int k=0; k<NIT; ++k){
    k_lhsQ  <<<dim3(55, BB), 256, 0, stream>>>(Qt, prm, lhs, k);
    k_invert<<<BB, 256, 0, stream>>>(lhs, inv);
    k_Pupd  <<<dim3(EE, BB), 256, 0, stream>>>(X, Qt, inv, P);
    k_lhsP  <<<dim3(55, BB), 256, 0, stream>>>(P, prm, lhs, k);
    k_invert<<<BB, 256, 0, stream>>>(lhs, inv);
    k_Qupd  <<<dim3(TT/256, BB), 256, 0, stream>>>(X, P, inv, Qt);
    k_gemm1 <<<dim3(EE, TT/1024, BB), 256, 0, stream>>>(Rm, A, Y, Om, Qt, P, prm, X, resid, k);
    k_gemm2 <<<dim3(FF, TT/1024, BB), 256, 0, stream>>>(Rt, resid, As, prm, A, k);
  }
}

// Round 2
// 2465.618 us; speedup vs baseline: 1.2459x; 1.2459x over previous
//
#include <hip/hip_runtime.h>
#include <stdint.h>

#define BB 16
#define EE 256
#define TT 4096
#define FF 512
#define RK 10
#define NIT 5

__device__ __forceinline__ unsigned short f2bf(float x){
  unsigned int u = __float_as_uint(x);
  unsigned int r = (u + 0x7FFFu + ((u >> 16) & 1u)) >> 16;
  return (unsigned short)r;
}
__device__ __forceinline__ float bf2f(unsigned short s){
  return __uint_as_float(((unsigned int)s) << 16);
}

// ---------------- setup kernels ----------------

__global__ void k_params(const float* lam_log, const float* mu_log,
                         const float* nu_log, const float* gl, float* prm){
  int k = threadIdx.x;
  if (k < NIT){
    float lam = expf(lam_log[k]);
    float mu  = expf(mu_log[k]);
    float nu  = expf(nu_log[k]);
    float gam = 1.0f/(1.0f+expf(-gl[k]));
    prm[k*8+0]=lam; prm[k*8+1]=mu; prm[k*8+2]=nu; prm[k*8+3]=gam; prm[k*8+4]=lam/nu;
  }
}

// X = Om*Y ; also emit Omega as bf16 (binary -> exact)
__global__ void k_initX(const float4* __restrict__ Y, const float4* __restrict__ Om,
                        float4* __restrict__ X, ushort4* __restrict__ Omb){
  int i = blockIdx.x*256 + threadIdx.x;
  float4 y = Y[i], o = Om[i];
  X[i] = make_float4(y.x*o.x, y.y*o.y, y.z*o.z, y.w*o.w);
  ushort4 ob; ob.x=f2bf(o.x); ob.y=f2bf(o.y); ob.z=f2bf(o.z); ob.w=f2bf(o.w);
  Omb[i] = ob;
}

__global__ void k_qtrans(const float* __restrict__ Q0, float* __restrict__ Qt){
  int idx = blockIdx.x*256 + threadIdx.x;   // b*TT + t
  int b = idx >> 12, t = idx & (TT-1);
  #pragma unroll
  for (int j=0;j<RK;j++)
    Qt[((size_t)b*RK + j)*TT + t] = Q0[(size_t)idx*RK + j];
}

__global__ void k_rtrans(const float* __restrict__ Rm, float* __restrict__ Rt){
  int f = blockIdx.x, b = blockIdx.y, e = threadIdx.x;
  Rt[((size_t)b*FF + f)*EE + e] = Rm[((size_t)b*EE + e)*FF + f];
}

// A_scale = (R*R)^T @ (Om*Om), stored bf16 (counts <=256 exact)
// 1D grid 32768, XCD-swizzled: group g=(tc,b) pinned to XCD g%8
__global__ void k_ascale(const float* __restrict__ Rt, const unsigned short* __restrict__ Omb,
                         unsigned short* __restrict__ As){
  int id = blockIdx.x;
  int xcd = id & 7;
  int within = id >> 3;            // 0..4095
  int f = within & (FF-1);
  int g = ((within >> 9) << 3) + xcd;  // 0..63
  int b = g >> 2;
  int t = (g & 3)*1024 + threadIdx.x*4;
  __shared__ int s_cnt;
  __shared__ short s_idx[EE];
  __shared__ float s_w[EE];
  if (threadIdx.x==0) s_cnt = 0;
  __syncthreads();
  {
    int e = threadIdx.x;
    float w = Rt[((size_t)b*FF + f)*EE + e];
    if (w != 0.0f){ int p = atomicAdd(&s_cnt,1); s_idx[p]=(short)e; s_w[p]=w*w; }
  }
  __syncthreads();
  int cnt = s_cnt;
  float4 acc = {0,0,0,0};
  const unsigned short* Ob = Omb + (size_t)b*EE*TT + t;
  for (int it=0; it<cnt; ++it){
    int e = s_idx[it]; float w2 = s_w[it];
    ushort4 ou = *(const ushort4*)(Ob + (size_t)e*TT);
    float ox=bf2f(ou.x), oy=bf2f(ou.y), oz=bf2f(ou.z), ow=bf2f(ou.w);
    acc.x += w2*ox*ox; acc.y += w2*oy*oy; acc.z += w2*oz*oz; acc.w += w2*ow*ow;
  }
  ushort4 r; r.x=f2bf(acc.x); r.y=f2bf(acc.y); r.z=f2bf(acc.z); r.w=f2bf(acc.w);
  *(ushort4*)(As + ((size_t)b*FF + f)*TT + t) = r;
}

// ---------------- per-iteration small kernels ----------------

__global__ void k_lhsQ(const float* __restrict__ Qt, const float* __restrict__ prm,
                       float* __restrict__ lhs, int k){
  int p = blockIdx.x, b = blockIdx.y;
  int i = 0, rem = p;
  while (rem >= i+1){ rem -= (i+1); ++i; }
  int j = rem;
  const float* qi = Qt + ((size_t)b*RK + i)*TT;
  const float* qj = Qt + ((size_t)b*RK + j)*TT;
  float a = 0.0f;
  for (int t = threadIdx.x*4; t < TT; t += 1024){
    float4 x = *(const float4*)(qi+t);
    float4 y = *(const float4*)(qj+t);
    a += x.x*y.x + x.y*y.y + x.z*y.z + x.w*y.w;
  }
  __shared__ float red[256];
  red[threadIdx.x] = a; __syncthreads();
  for (int s=128; s>0; s>>=1){
    if (threadIdx.x < s) red[threadIdx.x] += red[threadIdx.x+s];
    __syncthreads();
  }
  if (threadIdx.x==0){
    float v = red[0];
    if (i==j) v += prm[k*8+4];
    lhs[(b*RK+i)*RK + j] = v;
    lhs[(b*RK+j)*RK + i] = v;
  }
}

__global__ void k_lhsP(const float* __restrict__ P, const float* __restrict__ prm,
                       float* __restrict__ lhs, int k){
  int p = blockIdx.x, b = blockIdx.y;
  int i = 0, rem = p;
  while (rem >= i+1){ rem -= (i+1); ++i; }
  int j = rem;
  int e = threadIdx.x;
  const float* pr = P + ((size_t)b*EE + e)*RK;
  float a = pr[i]*pr[j];
  __shared__ float red[256];
  red[threadIdx.x] = a; __syncthreads();
  for (int s=128; s>0; s>>=1){
    if (threadIdx.x < s) red[threadIdx.x] += red[threadIdx.x+s];
    __syncthreads();
  }
  if (threadIdx.x==0){
    float v = red[0];
    if (i==j) v += prm[k*8+4];
    lhs[(b*RK+i)*RK + j] = v;
    lhs[(b*RK+j)*RK + i] = v;
  }
}

__global__ void k_invert(const float* __restrict__ lhs, float* __restrict__ inv){
  int b = blockIdx.x;
  __shared__ float aug[RK][2*RK];
  int tid = threadIdx.x;
  int i = tid / (2*RK), j = tid % (2*RK);
  bool act = tid < RK*2*RK;
  if (act) aug[i][j] = (j < RK) ? lhs[(b*RK+i)*RK + j] : ((j-RK)==i ? 1.0f : 0.0f);
  __syncthreads();
  for (int kk=0; kk<RK; ++kk){
    float pinv = 1.0f / aug[kk][kk];
    __syncthreads();
    if (act && i==kk) aug[i][j] *= pinv;
    __syncthreads();
    float factor = (act && i!=kk) ? aug[i][kk] : 0.0f;
    float pivrow = act ? aug[kk][j] : 0.0f;
    __syncthreads();
    if (act && i!=kk) aug[i][j] -= factor * pivrow;
    __syncthreads();
  }
  if (act && j >= RK) inv[(b*RK+i)*RK + (j-RK)] = aug[i][j];
}

__global__ void k_Pupd(const float* __restrict__ X, const float* __restrict__ Qt,
                       const float* __restrict__ inv, float* __restrict__ P){
  int e = blockIdx.x, b = blockIdx.y;
  const float* xr = X + ((size_t)b*EE + e)*TT;
  const float* qb = Qt + (size_t)b*RK*TT;
  float acc[RK];
  #pragma unroll
  for (int j=0;j<RK;j++) acc[j]=0.0f;
  for (int t = threadIdx.x*4; t < TT; t += 1024){
    float4 x = *(const float4*)(xr+t);
    #pragma unroll
    for (int j=0;j<RK;j++){
      float4 q = *(const float4*)(qb + (size_t)j*TT + t);
      acc[j] += x.x*q.x + x.y*q.y + x.z*q.z + x.w*q.w;
    }
  }
  __shared__ float partial[4][RK];
  int lane = threadIdx.x & 63, wv = threadIdx.x >> 6;
  #pragma unroll
  for (int j=0;j<RK;j++){
    float v = acc[j];
    for (int s=32;s>0;s>>=1) v += __shfl_down(v, s, 64);
    if (lane==0) partial[wv][j] = v;
  }
  __syncthreads();
  if (threadIdx.x < RK){
    int i = threadIdx.x;
    float out = 0.0f;
    #pragma unroll
    for (int j=0;j<RK;j++){
      float xq = partial[0][j]+partial[1][j]+partial[2][j]+partial[3][j];
      out += xq * inv[(b*RK+j)*RK + i];
    }
    P[((size_t)b*EE + e)*RK + i] = out;
  }
}

__global__ void k_Qupd(const float* __restrict__ X, const float* __restrict__ P,
                       const float* __restrict__ inv, float* __restrict__ Qt){
  int b = blockIdx.y;
  int t = blockIdx.x*256 + threadIdx.x;
  __shared__ float sP[EE*RK];
  __shared__ float sInv[RK*RK];
  for (int i=threadIdx.x; i<EE*RK; i+=256) sP[i] = P[(size_t)b*EE*RK + i];
  if (threadIdx.x < RK*RK) sInv[threadIdx.x] = inv[b*RK*RK + threadIdx.x];
  __syncthreads();
  float acc[RK];
  #pragma unroll
  for (int j=0;j<RK;j++) acc[j]=0.0f;
  const float* xb = X + (size_t)b*EE*TT + t;
  for (int e=0;e<EE;e++){
    float x = xb[(size_t)e*TT];
    #pragma unroll
    for (int j=0;j<RK;j++) acc[j] += x * sP[e*RK+j];
  }
  #pragma unroll
  for (int i=0;i<RK;i++){
    float q = 0.0f;
    #pragma unroll
    for (int j=0;j<RK;j++) q += acc[j]*sInv[j*RK+i];
    Qt[((size_t)b*RK + i)*TT + t] = q;
  }
}

// ---------------- big fused kernels ----------------

// RA = R@A (sparse row-sum), fused X-update + resid(bf16); 1D grid 16384, XCD-swizzled
__global__ void k_gemm1(const float* __restrict__ Rm, const float* __restrict__ A,
                        const float* __restrict__ Y, const unsigned short* __restrict__ Omb,
                        const float* __restrict__ Qt, const float* __restrict__ P,
                        const float* __restrict__ prm, float* __restrict__ X,
                        unsigned short* __restrict__ resid, int k){
  int id = blockIdx.x;
  int xcd = id & 7;
  int within = id >> 3;                 // 0..2047
  int e = within & (EE-1);
  int g = ((within >> 8) << 3) + xcd;   // group 0..63 -> pinned to XCD g%8
  int b = g >> 2;
  int t = (g & 3)*1024 + threadIdx.x*4;
  __shared__ int s_cnt;
  __shared__ short s_idx[FF];
  __shared__ float s_w[FF];
  __shared__ float sPe[RK];
  if (threadIdx.x==0) s_cnt = 0;
  __syncthreads();
  {
    const float* rrow = Rm + ((size_t)b*EE + e)*FF;
    for (int f=threadIdx.x; f<FF; f+=256){
      float w = rrow[f];
      if (w != 0.0f){ int p = atomicAdd(&s_cnt,1); s_idx[p]=(short)f; s_w[p]=w; }
    }
    if (threadIdx.x < RK) sPe[threadIdx.x] = P[((size_t)b*EE + e)*RK + threadIdx.x];
  }
  __syncthreads();
  int cnt = s_cnt;
  float4 ra = {0,0,0,0};
  const float* Ab = A + (size_t)b*FF*TT + t;
  for (int it=0; it<cnt; ++it){
    int f = s_idx[it]; float w = s_w[it];
    float4 a4 = *(const float4*)(Ab + (size_t)f*TT);
    ra.x += w*a4.x; ra.y += w*a4.y; ra.z += w*a4.z; ra.w += w*a4.w;
  }
  float4 pq = {0,0,0,0};
  const float* qb = Qt + (size_t)b*RK*TT + t;
  #pragma unroll
  for (int j=0;j<RK;j++){
    float4 q = *(const float4*)(qb + (size_t)j*TT);
    float pj = sPe[j];
    pq.x += pj*q.x; pq.y += pj*q.y; pq.z += pj*q.z; pq.w += pj*q.w;
  }
  float nu = prm[k*8+2];
  size_t off = ((size_t)b*EE + e)*TT + t;
  float4 y = *(const float4*)(Y + off);
  ushort4 ou = *(const ushort4*)(Omb + off);
  float4 o = make_float4(bf2f(ou.x), bf2f(ou.y), bf2f(ou.z), bf2f(ou.w));
  float4 xo; float rx, ry, rz, rw;
  {
    float d  = y.x - ra.x, om2 = o.x*o.x;
    xo.x = (om2*d + nu*pq.x) / (om2 + nu);
    rx = o.x*(y.x - xo.x - ra.x);
  }{
    float d  = y.y - ra.y, om2 = o.y*o.y;
    xo.y = (om2*d + nu*pq.y) / (om2 + nu);
    ry = o.y*(y.y - xo.y - ra.y);
  }{
    float d  = y.z - ra.z, om2 = o.z*o.z;
    xo.z = (om2*d + nu*pq.z) / (om2 + nu);
    rz = o.z*(y.z - xo.z - ra.z);
  }{
    float d  = y.w - ra.w, om2 = o.w*o.w;
    xo.w = (om2*d + nu*pq.w) / (om2 + nu);
    rw = o.w*(y.w - xo.w - ra.w);
  }
  *(float4*)(X + off) = xo;
  ushort4 rv; rv.x=f2bf(rx); rv.y=f2bf(ry); rv.z=f2bf(rz); rv.w=f2bf(rw);
  *(ushort4*)(resid + off) = rv;
}

__device__ __forceinline__ float aupd(float a, float g, unsigned short asu,
                                      float mu, float gamma){
  float as = bf2f(asu);
  bool no = (as == 0.0f);
  float rs = 1.0f / (no ? 1.0f : as);
  float ba = a + g*rs;
  float ad = copysignf(fmaxf(fabsf(ba) - mu*rs, 0.0f), ba);
  if (no) ad = 0.0f;
  return a + gamma*(ad - a);
}

// G = R^T@resid (sparse row-sum), fused A soft-threshold update; 1D grid 32768, XCD-swizzled
__global__ void k_gemm2(const float* __restrict__ Rt, const unsigned short* __restrict__ resid,
                        const unsigned short* __restrict__ As,
                        const float* __restrict__ prm, float* __restrict__ A, int k){
  int id = blockIdx.x;
  int xcd = id & 7;
  int within = id >> 3;                 // 0..4095
  int f = within & (FF-1);
  int g = ((within >> 9) << 3) + xcd;   // group 0..63
  int b = g >> 2;
  int t = (g & 3)*1024 + threadIdx.x*4;
  __shared__ int s_cnt;
  __shared__ short s_idx[EE];
  __shared__ float s_w[EE];
  if (threadIdx.x==0) s_cnt = 0;
  __syncthreads();
  {
    int e = threadIdx.x;
    float w = Rt[((size_t)b*FF + f)*EE + e];
    if (w != 0.0f){ int p = atomicAdd(&s_cnt,1); s_idx[p]=(short)e; s_w[p]=w; }
  }
  __syncthreads();
  int cnt = s_cnt;
  float4 gacc = {0,0,0,0};
  const unsigned short* rb = resid + (size_t)b*EE*TT + t;
  for (int it=0; it<cnt; ++it){
    int e = s_idx[it]; float w = s_w[it];
    ushort4 r4 = *(const ushort4*)(rb + (size_t)e*TT);
    gacc.x += w*bf2f(r4.x); gacc.y += w*bf2f(r4.y);
    gacc.z += w*bf2f(r4.z); gacc.w += w*bf2f(r4.w);
  }
  float mu = prm[k*8+1], gamma = prm[k*8+3];
  size_t off = ((size_t)b*FF + f)*TT + t;
  ushort4 asv = *(const ushort4*)(As + off);
  float4 a = *(float4*)(A + off);
  float4 an;
  an.x = aupd(a.x, gacc.x, asv.x, mu, gamma);
  an.y = aupd(a.y, gacc.y, asv.y, mu, gamma);
  an.z = aupd(a.z, gacc.z, asv.z, mu, gamma);
  an.w = aupd(a.w, gacc.w, asv.w, mu, gamma);
  *(float4*)(A + off) = an;
}

// ---------------- launch ----------------

extern "C" void kernel_launch(void* const* d_in, const int* in_sizes, int n_in,
                              void* d_out, int out_size, void* d_ws, size_t ws_size,
                              hipStream_t stream){
  const float* Y   = (const float*)d_in[0];
  const float* Rm  = (const float*)d_in[1];
  const float* Om  = (const float*)d_in[2];
  const float* P0  = (const float*)d_in[3];
  const float* Q0  = (const float*)d_in[4];
  const float* lam = (const float*)d_in[5];
  const float* mu  = (const float*)d_in[6];
  const float* nu  = (const float*)d_in[7];
  const float* gl  = (const float*)d_in[8];
  float* A = (float*)d_out;

  char* ws = (char*)d_ws;
  const size_t X_OFF   = 0;
  const size_t RES_OFF = X_OFF   + (size_t)BB*EE*TT*4;   // X: 67108864 B
  const size_t OMB_OFF = RES_OFF + (size_t)BB*EE*TT*2;   // resid bf16: 33554432 B
  const size_t AS_OFF  = OMB_OFF + (size_t)BB*EE*TT*2;   // Omb bf16: 33554432 B
  const size_t RT_OFF  = AS_OFF  + (size_t)BB*FF*TT*2;   // As bf16: 67108864 B
  const size_t QT_OFF  = RT_OFF  + (size_t)BB*FF*EE*4;
  const size_t P_OFF   = QT_OFF  + (size_t)BB*RK*TT*4;
  const size_t LHS_OFF = P_OFF   + (size_t)BB*EE*RK*4;
  const size_t INV_OFF = LHS_OFF + (size_t)BB*RK*RK*4;
  const size_t PRM_OFF = INV_OFF + (size_t)BB*RK*RK*4;

  float* X    = (float*)(ws + X_OFF);
  unsigned short* resid = (unsigned short*)(ws + RES_OFF);
  unsigned short* Omb   = (unsigned short*)(ws + OMB_OFF);
  unsigned short* As    = (unsigned short*)(ws + AS_OFF);
  float* Rt   = (float*)(ws + RT_OFF);
  float* Qt   = (float*)(ws + QT_OFF);
  float* P    = (float*)(ws + P_OFF);
  float* lhs  = (float*)(ws + LHS_OFF);
  float* inv  = (float*)(ws + INV_OFF);
  float* prm  = (float*)(ws + PRM_OFF);

  (void)P0; (void)Om; (void)in_sizes; (void)n_in; (void)ws_size;

  hipMemsetAsync(d_out, 0, (size_t)out_size*sizeof(float), stream);
  k_params<<<1, 64, 0, stream>>>(lam, mu, nu, gl, prm);
  k_initX<<<BB*EE*TT/4/256, 256, 0, stream>>>((const float4*)Y, (const float4*)Om,
                                              (float4*)X, (ushort4*)Omb);
  k_qtrans<<<BB*TT/256, 256, 0, stream>>>(Q0, Qt);
  k_rtrans<<<dim3(FF, BB), 256, 0, stream>>>(Rm, Rt);
  k_ascale<<<FF*4*BB, 256, 0, stream>>>(Rt, Omb, As);

  for (int k=0; k<NIT; ++k){
    k_lhsQ  <<<dim3(55, BB), 256, 0, stream>>>(Qt, prm, lhs, k);
    k_invert<<<BB, 256, 0, stream>>>(lhs, inv);
    k_Pupd  <<<dim3(EE, BB), 256, 0, stream>>>(X, Qt, inv, P);
    k_lhsP  <<<dim3(55, BB), 256, 0, stream>>>(P, prm, lhs, k);
    k_invert<<<BB, 256, 0, stream>>>(lhs, inv);
    k_Qupd  <<<dim3(TT/256, BB), 256, 0, stream>>>(X, P, inv, Qt);
    k_gemm1 <<<EE*4*BB, 256, 0, stream>>>(Rm, A, Y, Omb, Qt, P, prm, X, resid, k);
    k_gemm2 <<<FF*4*BB, 256, 0, stream>>>(Rt, resid, As, prm, A, k);
  }
}